// Round 9
// baseline (798.196 us; speedup 1.0000x reference)
//
#include <hip/hip_runtime.h>
#include <math.h>

#define BN 32
#define DN 128
#define GW 640            // 5*DN gate width
#define NSTEP 31
#define NT 1024

__device__ __forceinline__ float sigf(float x) { return 1.0f / (1.0f + expf(-x)); }

// ---------------------------------------------------------------- k1: leaf
// hidden0/cell0 = split(x_emb[bidx] @ W_leaf + b_leaf). One block per row,
// thread = output column; W reads coalesced, x row broadcast.
__global__ __launch_bounds__(256)
void leaf_kernel(const float* __restrict__ x_emb, const float* __restrict__ W_leaf,
                 const float* __restrict__ b_leaf, const int* __restrict__ bidx,
                 float* __restrict__ hidden0, float* __restrict__ cell0)
{
    const int i = blockIdx.x;        // row 0..31
    const int c = threadIdx.x;       // col 0..255
    const float* xr = x_emb + bidx[i] * DN;
    float acc = b_leaf[c];
    #pragma unroll 16
    for (int j = 0; j < DN; ++j) acc = fmaf(xr[j], W_leaf[j * 256 + c], acc);
    if (c < DN) hidden0[i * DN + c] = acc;
    else        cell0[i * DN + (c - DN)] = acc;
}

// ---------------------------------------------------------------- k2: tables
// Gh = hidden0 @ Wt_top (32x640), Gd = hidden0 @ Wt_bot,
// uT0/vT0 = (hidden0 @ A1_top/bot)^T. Row-split-4, 8 accumulators/thread.
__global__ __launch_bounds__(256)
void init2_kernel(const float* __restrict__ W_tree, const float* __restrict__ W_a1,
                  const float* __restrict__ hidden0,
                  float* __restrict__ Gh, float* __restrict__ Gd,
                  float* __restrict__ uT0, float* __restrict__ vT0)
{
    __shared__ float sh_h[BN][DN + 1];
    for (int i = threadIdx.x; i < BN * DN; i += 256)
        sh_h[i >> 7][i & 127] = hidden0[i];
    __syncthreads();
    const int task = blockIdx.x * 256 + threadIdx.x;   // grid 24*256 = 6144
    float acc[8];
    #pragma unroll
    for (int r = 0; r < 8; ++r) acc[r] = 0.0f;
    if (task < 5120) {                                  // G tables: 1280 cols x 4 rowgroups
        const int rg = task & 3, r0 = rg * 8;
        const int cc = task >> 2;                       // 0..1279
        const int c  = (cc < GW) ? cc : cc - GW;
        const float* Wt = W_tree + ((cc < GW) ? 0 : DN * GW) + c;
        #pragma unroll 8
        for (int k = 0; k < DN; ++k) {
            const float w = Wt[k * GW];
            #pragma unroll
            for (int r = 0; r < 8; ++r) acc[r] = fmaf(sh_h[r0 + r][k], w, acc[r]);
        }
        float* Gt = ((cc < GW) ? Gh : Gd) + c;
        #pragma unroll
        for (int r = 0; r < 8; ++r) Gt[(r0 + r) * GW] = acc[r];
    } else if (task < 6144) {                           // u/v: 256 cols x 4 rowgroups
        const int tt = task - 5120;
        const int rg = tt & 3, r0 = rg * 8;
        const int cc = tt >> 2;                         // 0..255
        const int k  = cc & 127;
        const float* Wp = W_a1 + ((cc < DN) ? 0 : DN * DN) + k;
        #pragma unroll 8
        for (int j = 0; j < DN; ++j) {
            const float w = Wp[j * DN];
            #pragma unroll
            for (int r = 0; r < 8; ++r) acc[r] = fmaf(sh_h[r0 + r][j], w, acc[r]);
        }
        float* dst = ((cc < DN) ? uT0 : vT0) + k * BN + r0;
        #pragma unroll
        for (int r = 0; r < 8; ++r) dst[r] = acc[r];
    }
}

// ---------------------------------------------------------------- k3: main loop
__global__ __launch_bounds__(NT)
void main_kernel(const float* __restrict__ W_tree, const float* __restrict__ b_tree,
                 const float* __restrict__ W_a1, const float* __restrict__ b_a1,
                 const float* __restrict__ W_a2, const float* __restrict__ b_a2,
                 const int* __restrict__ bidx,
                 const float* __restrict__ hidden0, const float* __restrict__ cell0,
                 const float* __restrict__ uT0, const float* __restrict__ vT0,
                 float* Gh, float* Gd,
                 float* __restrict__ out)
{
    __shared__ float sh_hidden[BN][DN + 1];   // pad 129: conflict-free row & col access
    __shared__ float sh_cell[BN][DN + 1];
    __shared__ float sh_uT[DN][BN + 1];       // pad 33
    __shared__ float sh_vT[DN][BN + 1];
    __shared__ float sh_score[BN * BN];
    __shared__ float sh_btree[GW];
    __shared__ float sh_w2[DN], sh_b1[DN];
    __shared__ int   sh_bidx[BN];
    __shared__ unsigned sh_maskbits;
    __shared__ int sh_head, sh_dep;
    __shared__ float sh_b2;

    const int tid  = threadIdx.x;
    const int lane = tid & 63;
    const int wid  = tid >> 6;

    // ---- stage state from ws
    for (int i = tid; i < BN * DN; i += NT) {
        sh_hidden[i >> 7][i & 127] = hidden0[i];
        sh_cell[i >> 7][i & 127]   = cell0[i];
        sh_uT[i >> 5][i & 31] = uT0[i];
        sh_vT[i >> 5][i & 31] = vT0[i];
    }
    for (int i = tid; i < GW; i += NT) sh_btree[i] = b_tree[i];
    if (tid < DN) { sh_w2[tid] = W_a2[tid]; sh_b1[tid] = b_a1[tid]; }
    if (tid < BN) sh_bidx[tid] = bidx[tid];
    if (tid == 0) { sh_b2 = b_a2[0]; sh_maskbits = 0xFFFFFFFFu; }
    __syncthreads();

    // per-thread constants for the score-refresh phase
    const int f_o = tid >> 4, f_sub = tid & 15;
    float w2r[8], b1r[8];
    #pragma unroll
    for (int i = 0; i < 8; ++i) { w2r[i] = sh_w2[f_sub * 8 + i]; b1r[i] = sh_b1[f_sub * 8 + i]; }

    // ---- initial 32x32 score matrix
    {
        const int h = tid >> 5, d = tid & 31;
        float acc = sh_b2;
        #pragma unroll 8
        for (int k = 0; k < DN; ++k) {
            const float pre = sh_uT[k][h] + sh_vT[k][d] + sh_b1[k];
            acc = fmaf(sh_w2[k], fmaxf(pre, 0.0f), acc);
        }
        sh_score[h * BN + d] = acc;
    }
    __syncthreads();

    float lps_sum = 0.0f, ents_sum = 0.0f;   // meaningful on wave 0 only
    int prev_head = -1;

    for (int t = 0; t < NSTEP; ++t) {
        // ===== phase 1: softmax/argmax on wave 0  ||  G-table row refresh on waves 1..10
        if (wid == 0) {
            const unsigned mbits = sh_maskbits;
            float s_[16]; bool v_[16];
            float m = -3.0e38f;
            #pragma unroll
            for (int i = 0; i < 16; ++i) {
                const int flat = i * 64 + lane;           // stride-64: conflict-free LDS
                const int h = flat >> 5, d = flat & 31;
                const float sc = sh_score[flat];
                const bool vv = (h != d) && ((mbits >> d) & 1u);
                s_[i] = sc; v_[i] = vv;
                m = vv ? fmaxf(m, sc) : m;
            }
            #pragma unroll
            for (int off = 1; off < 64; off <<= 1) m = fmaxf(m, __shfl_xor(m, off));
            float e = 0.0f, s1 = 0.0f; int cand = 0x7fffffff;
            #pragma unroll
            for (int i = 0; i < 16; ++i) {
                if (v_[i]) {
                    const float x = s_[i] - m;
                    const float ex = expf(x);
                    e += ex; s1 += ex * x;
                    if (s_[i] == m) cand = min(cand, i * 64 + lane);
                }
            }
            #pragma unroll
            for (int off = 1; off < 64; off <<= 1) {
                e    += __shfl_xor(e, off);
                s1   += __shfl_xor(s1, off);
                cand  = min(cand, __shfl_xor(cand, off));
            }
            const float logE = logf(e);
            lps_sum -= logE;                                   // logit[idx]==max -> lp = -logE
            ents_sum -= (s1 / e - logE) / logf((float)((BN - t) * (BN - 1)));
            if (lane == 0) {
                const int hh = cand >> 5, dd = cand & 31;
                sh_head = hh; sh_dep = dd;
                sh_maskbits = mbits & ~(1u << dd);
                out[BN * DN + 2 + 2 * t]     = (float)sh_bidx[hh];
                out[BN * DN + 2 + 2 * t + 1] = (float)sh_bidx[dd];
            }
        } else if (prev_head >= 0) {
            // refresh Gh[prev_head], Gd[prev_head] (hidden[prev_head] changed last step)
            const float* hrow = sh_hidden[prev_head];
            const int task = tid - 64;                     // 640 float2 column-pairs
            if (task < GW) {
                const int cc  = task * 2;                  // 0..1278 even
                const int col = (cc < GW) ? cc : cc - GW;
                const float2* Wt2 = (const float2*)(W_tree + ((cc < GW) ? 0 : DN * GW) + col);
                float ax = 0.0f, ay = 0.0f;
                #pragma unroll 16
                for (int k = 0; k < DN; ++k) {
                    const float2 w = Wt2[k * (GW / 2)];
                    const float hv = hrow[k];
                    ax = fmaf(hv, w.x, ax);
                    ay = fmaf(hv, w.y, ay);
                }
                float* Gt = ((cc < GW) ? Gh : Gd) + prev_head * GW + col;
                Gt[0] = ax; Gt[1] = ay;
            }
        }
        __syncthreads();

        const int head = sh_head, dep = sh_dep;

        // ===== phase 2: gate fetch (G tables) + nonlinearity + state update
        if (tid < DN) {
            const int k = tid;
            const float* gh = Gh + head * GW + k;
            const float* gd = Gd + dep  * GW + k;
            const float z0 = gh[0]      + gd[0]      + sh_btree[k];
            const float z1 = gh[DN]     + gd[DN]     + sh_btree[DN + k];
            const float z2 = gh[2 * DN] + gd[2 * DN] + sh_btree[2 * DN + k];
            const float z3 = gh[3 * DN] + gd[3 * DN] + sh_btree[3 * DN + k];
            const float z4 = gh[4 * DN] + gd[4 * DN] + sh_btree[4 * DN + k];
            const float ig = sigf(z0), fl = sigf(z1), fr = sigf(z2), og = sigf(z4);
            const float gg = tanhf(z3);
            const float c  = ig * gg + fl * sh_cell[head][k] + fr * sh_cell[dep][k];
            sh_cell[head][k]   = c;
            sh_hidden[head][k] = og * tanhf(c);
        }
        __syncthreads();

        // ===== phase 3: refresh u/v columns for row 'head'
        if (tid < 2 * DN) {
            const int k = tid & 127;
            const float* Wp = W_a1 + ((tid < DN) ? 0 : DN * DN) + k;
            const float* hrow = sh_hidden[head];
            float acc = 0.0f;
            #pragma unroll 32
            for (int j = 0; j < DN; ++j) acc = fmaf(hrow[j], Wp[j * DN], acc);
            if (tid < DN) sh_uT[k][head] = acc; else sh_vT[k][head] = acc;
        }
        __syncthreads();

        // ===== phase 4: refresh score row 'head' + column 'head' (16 threads/output)
        {
            const int hh = (f_o < BN) ? head : (f_o - BN);
            const int dd = (f_o < BN) ? f_o : head;
            float p = 0.0f;
            #pragma unroll
            for (int i = 0; i < 8; ++i) {
                const int k = f_sub * 8 + i;
                const float pre = sh_uT[k][hh] + sh_vT[k][dd] + b1r[i];
                p = fmaf(w2r[i], fmaxf(pre, 0.0f), p);
            }
            #pragma unroll
            for (int off = 8; off > 0; off >>= 1) p += __shfl_down(p, off, 16);
            if (f_sub == 0 && hh != dd) sh_score[hh * BN + dd] = p + sh_b2;
        }
        __syncthreads();

        prev_head = head;
    }

    // ---- outputs
    for (int w = tid; w < BN * DN; w += NT) out[w] = sh_hidden[w >> 7][w & 127];
    if (tid == 0) {
        out[BN * DN]     = lps_sum;
        out[BN * DN + 1] = ents_sum / (float)NSTEP;
    }
}

extern "C" void kernel_launch(void* const* d_in, const int* in_sizes, int n_in,
                              void* d_out, int out_size, void* d_ws, size_t ws_size,
                              hipStream_t stream) {
    const float* x_emb  = (const float*)d_in[0];
    const float* W_leaf = (const float*)d_in[1];
    const float* b_leaf = (const float*)d_in[2];
    const float* W_tree = (const float*)d_in[3];
    const float* b_tree = (const float*)d_in[4];
    const float* W_a1   = (const float*)d_in[5];
    const float* b_a1   = (const float*)d_in[6];
    const float* W_a2   = (const float*)d_in[7];
    const float* b_a2   = (const float*)d_in[8];
    const int*   bidx   = (const int*)d_in[9];
    float* out = (float*)d_out;

    // ws layout (floats): hidden0[4096] cell0[4096] uT0[4096] vT0[4096] Gh[20480] Gd[20480]
    float* ws      = (float*)d_ws;
    float* hidden0 = ws;
    float* cell0   = ws + 4096;
    float* uT0     = ws + 8192;
    float* vT0     = ws + 12288;
    float* Gh      = ws + 16384;
    float* Gd      = Gh + BN * GW;

    hipLaunchKernelGGL(leaf_kernel, dim3(BN), dim3(256), 0, stream,
                       x_emb, W_leaf, b_leaf, bidx, hidden0, cell0);
    hipLaunchKernelGGL(init2_kernel, dim3(24), dim3(256), 0, stream,
                       W_tree, W_a1, hidden0, Gh, Gd, uT0, vT0);
    hipLaunchKernelGGL(main_kernel, dim3(1), dim3(NT), 0, stream,
                       W_tree, b_tree, W_a1, b_a1, W_a2, b_a2, bidx,
                       hidden0, cell0, uT0, vT0, Gh, Gd, out);
}